// Round 10
// baseline (423.098 us; speedup 1.0000x reference)
//
#include <hip/hip_runtime.h>

#define HD   128   // hidden dim
#define TM   64    // node rows per block in the GIN layer kernel (512 threads)
#define TM0  32    // rows per block for layer-0 kernel (256 threads, unchanged)
#define SYB  136   // fp16 LDS stride
#define ECAP 768   // staged edges per tile (block avg ~384 at TM=64)
#define ECP0 512   // staged edges per tile for layer-0 blocks

typedef __attribute__((ext_vector_type(8))) short    short8;
typedef __attribute__((ext_vector_type(8))) _Float16 half8;
typedef __attribute__((ext_vector_type(4))) float    float4v;

// split fp32 -> fp16 hi + fp16 lo; v == hi + lo to ~2^-22 rel (lo may be denormal)
__device__ __forceinline__ void split_h16(float v, _Float16& hi, _Float16& lo) {
    hi = (_Float16)v;
    lo = (_Float16)(v - (float)hi);
}

// ------------------------------------------------ fused preamble ----
// weight-split | emb->fp16 table | degree in one launch (independent work)
__global__ void k_pre(const float* __restrict__ emb, _Float16* __restrict__ emb16,
                      int ctot,
                      const float* __restrict__ W1, const float* __restrict__ W2,
                      _Float16* __restrict__ wh, _Float16* __restrict__ wl, int wtot,
                      const int* __restrict__ dst, int* __restrict__ deg, int e,
                      int nbW, int nbC)
{
    int b = blockIdx.x, tx = threadIdx.x;
    if (b < nbW) {
        // ---- weight split into B-frags (fp16 hi/lo)
        // frag idx f = ((ct*4 + kb)*64 + lane)*8 + j holds
        // W[kb*32 + (lane>>4)*8 + j][ct*16 + (lane&15)]  (B-operand of 16x16x32)
        int g = b * 256 + tx;
        if (g < wtot) {
            int f  = g & 16383;
            int m  = (g >> 14) & 1;
            int l  = g >> 15;
            int j    = f & 7;
            int lane = (f >> 3) & 63;
            int kb   = (f >> 9) & 3;
            int ct   = f >> 11;
            int k  = kb * 32 + (lane >> 4) * 8 + j;
            int nn = ct * 16 + (lane & 15);
            const float* W = m ? W2 : W1;
            float v = W[(size_t)l * 16384 + k * 128 + nn];
            _Float16 h, lo; split_h16(v, h, lo);
            wh[g] = h; wl[g] = lo;
        }
    } else if (b < nbW + nbC) {
        // ---- emb fp32 -> fp16 table (VOCAB x HD, 8 elems/thread)
        int g = (b - nbW) * 256 + tx;
        if (g < ctot) {
            const float4* e4 = (const float4*)emb + (size_t)g * 2;
            float4 a = e4[0], c = e4[1];
            half8 h;
            h[0] = (_Float16)a.x; h[1] = (_Float16)a.y; h[2] = (_Float16)a.z; h[3] = (_Float16)a.w;
            h[4] = (_Float16)c.x; h[5] = (_Float16)c.y; h[6] = (_Float16)c.z; h[7] = (_Float16)c.w;
            ((half8*)emb16)[g] = h;
        }
    } else {
        // ---- degree
        int i = (b - nbW - nbC) * 256 + tx;
        if (i < e) atomicAdd(&deg[dst[i]], 1);
    }
}

// ------------------------------------------------------------- CSR build ----
__global__ void k_scan1(const int* __restrict__ deg, int* __restrict__ rp,
                        int* __restrict__ bsum, int n)
{
    __shared__ int s[1024];
    int t = threadIdx.x;
    int i = blockIdx.x * 1024 + t;
    int v = (i < n) ? deg[i] : 0;
    s[t] = v; __syncthreads();
    for (int off = 1; off < 1024; off <<= 1) {
        int tmp = (t >= off) ? s[t - off] : 0;
        __syncthreads();
        s[t] += tmp;
        __syncthreads();
    }
    if (i < n) rp[i] = s[t] - v;
    if (t == 1023) bsum[blockIdx.x] = s[1023];
}

__global__ void k_scan2(int* __restrict__ bsum, int nb)
{
    __shared__ int s[128];
    int t = threadIdx.x;
    int v = (t < nb) ? bsum[t] : 0;
    s[t] = v; __syncthreads();
    for (int off = 1; off < 128; off <<= 1) {
        int tmp = (t >= off) ? s[t - off] : 0;
        __syncthreads();
        s[t] += tmp;
        __syncthreads();
    }
    if (t < nb) bsum[t] = s[t] - v;
}

__global__ void k_scan3(int* __restrict__ rp, const int* __restrict__ bsum, int n, int e)
{
    int i = blockIdx.x * 1024 + threadIdx.x;
    if (i < n) rp[i] += bsum[blockIdx.x];
    if (i == 0) rp[n] = e;
}

__global__ void k_fill(const int* __restrict__ src, const int* __restrict__ dst,
                       const int* __restrict__ rp, int* __restrict__ fill,
                       int* __restrict__ ci, int e)
{
    int i = blockIdx.x * 256 + threadIdx.x;
    if (i < e) {
        int d = dst[i];
        int p = atomicAdd(&fill[d], 1);
        ci[rp[d] + p] = src[i];
    }
}

// ------------------------------------------------------- fused GIN layer ----
// TM=64 rows, 512 threads, 8 waves: wave wv = (row-half wv>>2, col-tile wv&3).
// Halves block count vs TM=32 -> halves per-layer skeleton chains and
// per-block weight reload traffic (W hi/lo read 2x per block instead of
// 1x per 32-row block).
__global__ __launch_bounds__(512, 4)
void k_gin(const _Float16* __restrict__ xin, _Float16* __restrict__ xout,
           const int* __restrict__ rp, const int* __restrict__ ci,
           const _Float16* __restrict__ w1h, const _Float16* __restrict__ w1l,
           const _Float16* __restrict__ w2h, const _Float16* __restrict__ w2l,
           const float* __restrict__ b1, const float* __restrict__ b2,
           int n)
{
    __shared__ _Float16 sA[TM * SYB];   // Y tile, then H tile (fp16)
    __shared__ int      sCI[ECAP];      // staged neighbor indices for the block

    const int tx   = threadIdx.x;
    const int row0 = blockIdx.x * TM;
    const int wv   = tx >> 6, lane = tx & 63;
    const int quad = lane >> 4, lrow = lane & 15;
    const int c2   = wv & 3;            // col tile (32 cols)
    const int rh   = wv >> 2;           // row half (32 rows)

    // ---- aggregation: Y[row] = x[row] + sum_{j} x[j]
    // 64 groups of 8 lanes, one row each (same per-group work as TM=32 version)
    {
        const int rl = tx >> 3, part = tx & 7;
        int node = row0 + rl;
        if (node >= n) node = n - 1;             // clamped rows compute garbage, never stored
        const half8* xr = (const half8*)(xin + (size_t)node * HD);
        half8 xs0 = xr[part * 2 + 0];
        half8 xs1 = xr[part * 2 + 1];
        float acc[2][8];
#pragma unroll
        for (int k = 0; k < 8; ++k) { acc[0][k] = (float)xs0[k]; acc[1][k] = (float)xs1[k]; }

        const int e0 = rp[node], e1 = rp[node + 1];
        const int eb0 = rp[row0];
        const int ebN = rp[(row0 + TM < n) ? (row0 + TM) : n];

        for (int t0 = eb0; t0 < ebN; t0 += ECAP) {
            const int t1 = (t0 + ECAP < ebN) ? (t0 + ECAP) : ebN;
            for (int i = tx; i < t1 - t0; i += 512) sCI[i] = ci[t0 + i];
            __syncthreads();

            int a = (e0 > t0) ? e0 : t0;
            int b = (e1 < t1) ? e1 : t1;
            for (int base = a; base < b; base += 8) {
                half8 u[8][2];
#pragma unroll
                for (int q = 0; q < 8; ++q) {    // predicated: masked groups issue no traffic
                    if (base + q < b) {
                        int c = sCI[base + q - t0];
                        const half8* xc = (const half8*)(xin + (size_t)c * HD);
                        u[q][0] = xc[part * 2 + 0];
                        u[q][1] = xc[part * 2 + 1];
                    }
                }
#pragma unroll
                for (int q = 0; q < 8; ++q) {
                    if (base + q < b) {
#pragma unroll
                        for (int k = 0; k < 8; ++k) {
                            acc[0][k] += (float)u[q][0][k];
                            acc[1][k] += (float)u[q][1][k];
                        }
                    }
                }
            }
            __syncthreads();   // all groups done with this sCI tile
        }

        // fp32 -> fp16 into LDS (elems part*16 + q*8 + j)
#pragma unroll
        for (int q = 0; q < 2; ++q) {
            half8 h8;
#pragma unroll
            for (int k = 0; k < 8; ++k) h8[k] = (_Float16)acc[q][k];
            *(half8*)&sA[rl * SYB + part * 16 + q * 8] = h8;
        }
    }

    // B1 hi frags + bias (wave's 2 col sub-tiles of 16)
    half8 Bh[2][4];
    {
        const half8* h8 = (const half8*)w1h;
#pragma unroll
        for (int c = 0; c < 2; ++c)
#pragma unroll
            for (int kb = 0; kb < 4; ++kb)
                Bh[c][kb] = h8[((2 * c2 + c) * 4 + kb) * 64 + lane];
    }
    float bb0 = b1[(2 * c2 + 0) * 16 + lrow];
    float bb1 = b1[(2 * c2 + 1) * 16 + lrow];
    __syncthreads();

    // ---- GEMM1: H = relu(Y @ W1 + b1); wave rows [rh*32, rh*32+32), cols [32*c2, +32)
    float4v acc1[2][2];
#pragma unroll
    for (int rt = 0; rt < 2; ++rt) {
        acc1[rt][0] = (float4v){bb0, bb0, bb0, bb0};
        acc1[rt][1] = (float4v){bb1, bb1, bb1, bb1};
    }
    {
        const half8* l8 = (const half8*)w1l;
#pragma unroll
        for (int kb = 0; kb < 4; ++kb) {
            half8 Ah[2];
#pragma unroll
            for (int rt = 0; rt < 2; ++rt)
                Ah[rt] = *(const half8*)&sA[(rh * 32 + rt * 16 + lrow) * SYB + kb * 32 + quad * 8];
            half8 Bl0 = l8[((2 * c2 + 0) * 4 + kb) * 64 + lane];
            half8 Bl1 = l8[((2 * c2 + 1) * 4 + kb) * 64 + lane];
#pragma unroll
            for (int rt = 0; rt < 2; ++rt) {
                acc1[rt][0] = __builtin_amdgcn_mfma_f32_16x16x32_f16(Ah[rt], Bh[0][kb], acc1[rt][0], 0, 0, 0);
                acc1[rt][0] = __builtin_amdgcn_mfma_f32_16x16x32_f16(Ah[rt], Bl0,       acc1[rt][0], 0, 0, 0);
                acc1[rt][1] = __builtin_amdgcn_mfma_f32_16x16x32_f16(Ah[rt], Bh[1][kb], acc1[rt][1], 0, 0, 0);
                acc1[rt][1] = __builtin_amdgcn_mfma_f32_16x16x32_f16(Ah[rt], Bl1,       acc1[rt][1], 0, 0, 0);
            }
        }
    }

    // B2 hi frags + bias
    half8 Bh2[2][4];
    {
        const half8* h8 = (const half8*)w2h;
#pragma unroll
        for (int c = 0; c < 2; ++c)
#pragma unroll
            for (int kb = 0; kb < 4; ++kb)
                Bh2[c][kb] = h8[((2 * c2 + c) * 4 + kb) * 64 + lane];
    }
    float cb0 = b2[(2 * c2 + 0) * 16 + lrow];
    float cb1 = b2[(2 * c2 + 1) * 16 + lrow];

    __syncthreads();   // all waves done reading Y from LDS

    // H (relu) -> fp16 into sA (overwrite Y); each wave writes its rows x cols
#pragma unroll
    for (int rt = 0; rt < 2; ++rt)
#pragma unroll
        for (int c = 0; c < 2; ++c) {
            int col = (2 * c2 + c) * 16 + lrow;
#pragma unroll
            for (int r = 0; r < 4; ++r) {
                int row = rh * 32 + rt * 16 + quad * 4 + r;
                sA[row * SYB + col] = (_Float16)fmaxf(acc1[rt][c][r], 0.f);
            }
        }
    __syncthreads();

    // ---- GEMM2: X' = relu(H @ W2 + b2)
    float4v acc2[2][2];
#pragma unroll
    for (int rt = 0; rt < 2; ++rt) {
        acc2[rt][0] = (float4v){cb0, cb0, cb0, cb0};
        acc2[rt][1] = (float4v){cb1, cb1, cb1, cb1};
    }
    {
        const half8* l8 = (const half8*)w2l;
#pragma unroll
        for (int kb = 0; kb < 4; ++kb) {
            half8 Ah[2];
#pragma unroll
            for (int rt = 0; rt < 2; ++rt)
                Ah[rt] = *(const half8*)&sA[(rh * 32 + rt * 16 + lrow) * SYB + kb * 32 + quad * 8];
            half8 Bl0 = l8[((2 * c2 + 0) * 4 + kb) * 64 + lane];
            half8 Bl1 = l8[((2 * c2 + 1) * 4 + kb) * 64 + lane];
#pragma unroll
            for (int rt = 0; rt < 2; ++rt) {
                acc2[rt][0] = __builtin_amdgcn_mfma_f32_16x16x32_f16(Ah[rt], Bh2[0][kb], acc2[rt][0], 0, 0, 0);
                acc2[rt][0] = __builtin_amdgcn_mfma_f32_16x16x32_f16(Ah[rt], Bl0,        acc2[rt][0], 0, 0, 0);
                acc2[rt][1] = __builtin_amdgcn_mfma_f32_16x16x32_f16(Ah[rt], Bh2[1][kb], acc2[rt][1], 0, 0, 0);
                acc2[rt][1] = __builtin_amdgcn_mfma_f32_16x16x32_f16(Ah[rt], Bl1,        acc2[rt][1], 0, 0, 0);
            }
        }
    }

    // epilogue: relu + store fp16
#pragma unroll
    for (int rt = 0; rt < 2; ++rt)
#pragma unroll
        for (int c = 0; c < 2; ++c) {
            int col = (2 * c2 + c) * 16 + lrow;
#pragma unroll
            for (int r = 0; r < 4; ++r) {
                int node = row0 + rh * 32 + rt * 16 + quad * 4 + r;
                if (node < n)
                    xout[(size_t)node * HD + col] = (_Float16)fmaxf(acc2[rt][c][r], 0.f);
            }
        }
}

// ---------------------------------------------- layer-0 fused GIN layer ----
// x0 = emb[tok]: gather tok[src] (4 B, L2-resident) + 32 KB fp16 table (L1).
// TM0=32 rows, 256 threads (unchanged from R9 to isolate the TM=64 variable).
__global__ __launch_bounds__(256, 4)
void k_gin0(const int* __restrict__ tok, const _Float16* __restrict__ emb16,
            _Float16* __restrict__ xout,
            const int* __restrict__ rp, const int* __restrict__ ci,
            const _Float16* __restrict__ w1h, const _Float16* __restrict__ w1l,
            const _Float16* __restrict__ w2h, const _Float16* __restrict__ w2l,
            const float* __restrict__ b1, const float* __restrict__ b2,
            int n)
{
    __shared__ _Float16 sA[TM0 * SYB];
    __shared__ int      sCI[ECP0];

    const int tx   = threadIdx.x;
    const int row0 = blockIdx.x * TM0;
    const int wv   = tx >> 6, lane = tx & 63;
    const int quad = lane >> 4, lrow = lane & 15;

    // ---- aggregation via fp16 emb-table lookup
    {
        const int rl = tx >> 3, part = tx & 7;
        int node = row0 + rl;
        if (node >= n) node = n - 1;
        int tself = tok[node];
        const half8* er = (const half8*)(emb16 + (size_t)tself * HD);
        half8 xs0 = er[part * 2 + 0];
        half8 xs1 = er[part * 2 + 1];
        float acc[2][8];
#pragma unroll
        for (int k = 0; k < 8; ++k) { acc[0][k] = (float)xs0[k]; acc[1][k] = (float)xs1[k]; }

        const int e0 = rp[node], e1 = rp[node + 1];
        const int eb0 = rp[row0];
        const int ebN = rp[(row0 + TM0 < n) ? (row0 + TM0) : n];

        for (int t0 = eb0; t0 < ebN; t0 += ECP0) {
            const int t1 = (t0 + ECP0 < ebN) ? (t0 + ECP0) : ebN;
            for (int i = tx; i < t1 - t0; i += 256) sCI[i] = ci[t0 + i];
            __syncthreads();

            int a = (e0 > t0) ? e0 : t0;
            int b = (e1 < t1) ? e1 : t1;
            for (int base = a; base < b; base += 8) {
                int tq[8];
#pragma unroll
                for (int q = 0; q < 8; ++q) {
                    if (base + q < b) tq[q] = tok[sCI[base + q - t0]];
                }
                half8 u[8][2];
#pragma unroll
                for (int q = 0; q < 8; ++q) {
                    if (base + q < b) {
                        const half8* xc = (const half8*)(emb16 + (size_t)tq[q] * HD);
                        u[q][0] = xc[part * 2 + 0];
                        u[q][1] = xc[part * 2 + 1];
                    }
                }
#pragma unroll
                for (int q = 0; q < 8; ++q) {
                    if (base + q < b) {
#pragma unroll
                        for (int k = 0; k < 8; ++k) {
                            acc[0][k] += (float)u[q][0][k];
                            acc[1][k] += (float)u[q][1][k];
                        }
                    }
                }
            }
            __syncthreads();
        }

#pragma unroll
        for (int q = 0; q < 2; ++q) {
            half8 h8;
#pragma unroll
            for (int k = 0; k < 8; ++k) h8[k] = (_Float16)acc[q][k];
            *(half8*)&sA[rl * SYB + part * 16 + q * 8] = h8;
        }
    }

    // B1 hi frags + bias
    half8 Bh[2][4];
    {
        const half8* h8 = (const half8*)w1h;
#pragma unroll
        for (int c = 0; c < 2; ++c)
#pragma unroll
            for (int kb = 0; kb < 4; ++kb)
                Bh[c][kb] = h8[((2 * wv + c) * 4 + kb) * 64 + lane];
    }
    float bb0 = b1[(2 * wv + 0) * 16 + lrow];
    float bb1 = b1[(2 * wv + 1) * 16 + lrow];
    __syncthreads();

    float4v acc1[2][2];
#pragma unroll
    for (int rt = 0; rt < 2; ++rt) {
        acc1[rt][0] = (float4v){bb0, bb0, bb0, bb0};
        acc1[rt][1] = (float4v){bb1, bb1, bb1, bb1};
    }
    {
        const half8* l8 = (const half8*)w1l;
#pragma unroll
        for (int kb = 0; kb < 4; ++kb) {
            half8 Ah[2];
#pragma unroll
            for (int rt = 0; rt < 2; ++rt)
                Ah[rt] = *(const half8*)&sA[(rt * 16 + lrow) * SYB + kb * 32 + quad * 8];
            half8 Bl0 = l8[((2 * wv + 0) * 4 + kb) * 64 + lane];
            half8 Bl1 = l8[((2 * wv + 1) * 4 + kb) * 64 + lane];
#pragma unroll
            for (int rt = 0; rt < 2; ++rt) {
                acc1[rt][0] = __builtin_amdgcn_mfma_f32_16x16x32_f16(Ah[rt], Bh[0][kb], acc1[rt][0], 0, 0, 0);
                acc1[rt][0] = __builtin_amdgcn_mfma_f32_16x16x32_f16(Ah[rt], Bl0,       acc1[rt][0], 0, 0, 0);
                acc1[rt][1] = __builtin_amdgcn_mfma_f32_16x16x32_f16(Ah[rt], Bh[1][kb], acc1[rt][1], 0, 0, 0);
                acc1[rt][1] = __builtin_amdgcn_mfma_f32_16x16x32_f16(Ah[rt], Bl1,       acc1[rt][1], 0, 0, 0);
            }
        }
    }

    half8 Bh2[2][4];
    {
        const half8* h8 = (const half8*)w2h;
#pragma unroll
        for (int c = 0; c < 2; ++c)
#pragma unroll
            for (int kb = 0; kb < 4; ++kb)
                Bh2[c][kb] = h8[((2 * wv + c) * 4 + kb) * 64 + lane];
    }
    float cb0 = b2[(2 * wv + 0) * 16 + lrow];
    float cb1 = b2[(2 * wv + 1) * 16 + lrow];

    __syncthreads();

#pragma unroll
    for (int rt = 0; rt < 2; ++rt)
#pragma unroll
        for (int c = 0; c < 2; ++c) {
            int col = (2 * wv + c) * 16 + lrow;
#pragma unroll
            for (int r = 0; r < 4; ++r) {
                int row = rt * 16 + quad * 4 + r;
                sA[row * SYB + col] = (_Float16)fmaxf(acc1[rt][c][r], 0.f);
            }
        }
    __syncthreads();

    float4v acc2[2][2];
#pragma unroll
    for (int rt = 0; rt < 2; ++rt) {
        acc2[rt][0] = (float4v){cb0, cb0, cb0, cb0};
        acc2[rt][1] = (float4v){cb1, cb1, cb1, cb1};
    }
    {
        const half8* l8 = (const half8*)w2l;
#pragma unroll
        for (int kb = 0; kb < 4; ++kb) {
            half8 Ah[2];
#pragma unroll
            for (int rt = 0; rt < 2; ++rt)
                Ah[rt] = *(const half8*)&sA[(rt * 16 + lrow) * SYB + kb * 32 + quad * 8];
            half8 Bl0 = l8[((2 * wv + 0) * 4 + kb) * 64 + lane];
            half8 Bl1 = l8[((2 * wv + 1) * 4 + kb) * 64 + lane];
#pragma unroll
            for (int rt = 0; rt < 2; ++rt) {
                acc2[rt][0] = __builtin_amdgcn_mfma_f32_16x16x32_f16(Ah[rt], Bh2[0][kb], acc2[rt][0], 0, 0, 0);
                acc2[rt][0] = __builtin_amdgcn_mfma_f32_16x16x32_f16(Ah[rt], Bl0,        acc2[rt][0], 0, 0, 0);
                acc2[rt][1] = __builtin_amdgcn_mfma_f32_16x16x32_f16(Ah[rt], Bh2[1][kb], acc2[rt][1], 0, 0, 0);
                acc2[rt][1] = __builtin_amdgcn_mfma_f32_16x16x32_f16(Ah[rt], Bl1,        acc2[rt][1], 0, 0, 0);
            }
        }
    }

#pragma unroll
    for (int rt = 0; rt < 2; ++rt)
#pragma unroll
        for (int c = 0; c < 2; ++c) {
            int col = (2 * wv + c) * 16 + lrow;
#pragma unroll
            for (int r = 0; r < 4; ++r) {
                int node = row0 + rt * 16 + quad * 4 + r;
                if (node < n)
                    xout[(size_t)node * HD + col] = (_Float16)fmaxf(acc2[rt][c][r], 0.f);
            }
        }
}

// ------------------------------------------------------------------ pool ----
__global__ void k_pool(const _Float16* __restrict__ x, const int* __restrict__ batch,
                       float* __restrict__ out, int n)
{
    __shared__ float sp[HD];
    int g = blockIdx.x;
    int t = threadIdx.x & (HD - 1);
    int h = threadIdx.x >> 7;          // strand 0/1
    int lo = 0, hi = n;
    while (lo < hi) { int m = (lo + hi) >> 1; if (batch[m] < g) lo = m + 1; else hi = m; }
    int s = lo;
    hi = n;
    while (lo < hi) { int m = (lo + hi) >> 1; if (batch[m] < g + 1) lo = m + 1; else hi = m; }
    int e = lo;
    float sum = 0.f;
    int i = s + h;
    for (; i + 2 < e; i += 4) {
        float v0 = (float)x[(size_t)i * HD + t];
        float v1 = (float)x[(size_t)(i + 2) * HD + t];
        sum += v0 + v1;
    }
    if (i < e) sum += (float)x[(size_t)i * HD + t];
    if (h == 1) sp[t] = sum;
    __syncthreads();
    if (h == 0) {
        int cnt = e - s;
        float tot = sum + sp[t];
        out[(size_t)g * HD + t] = (cnt > 0) ? tot / (float)cnt : 0.f;
    }
}

// ---------------------------------------------------------------- launch ----
extern "C" void kernel_launch(void* const* d_in, const int* in_sizes, int n_in,
                              void* d_out, int out_size, void* d_ws, size_t ws_size,
                              hipStream_t stream)
{
    const int*   tok   = (const int*)d_in[0];
    const int*   eidx  = (const int*)d_in[1];
    const int*   batch = (const int*)d_in[2];
    const float* emb   = (const float*)d_in[3];
    const float* W1    = (const float*)d_in[4];
    const float* b1    = (const float*)d_in[5];
    const float* W2    = (const float*)d_in[6];
    const float* b2    = (const float*)d_in[7];
    float* out = (float*)d_out;

    const int n      = in_sizes[0];
    const int e      = in_sizes[1] / 2;
    const int ngraph = out_size / HD;
    const int L      = in_sizes[4] / (HD * HD);
    const int vocab  = in_sizes[3] / HD;     // in_sizes are ELEMENT counts (fp32)
    const int* src = eidx;
    const int* dst = eidx + e;

    char* w = (char*)d_ws;
    size_t off = 0;
    auto alloc = [&](size_t bytes) -> void* {
        void* p = w + off;
        off = (off + bytes + 255) & ~(size_t)255;
        return p;
    };
    _Float16* xa = (_Float16*)alloc((size_t)(n + TM) * HD * 2);
    _Float16* xb = (_Float16*)alloc((size_t)(n + TM) * HD * 2);
    _Float16* emb16 = (_Float16*)alloc((size_t)vocab * HD * 2);
    int* rp    = (int*)alloc((size_t)(n + 1) * 4);
    // zero-init group: deg, fillc contiguous -> ONE memset
    size_t zoff = off;
    int* deg   = (int*)alloc((size_t)n * 4);
    int* fillc = (int*)alloc((size_t)n * 4);
    size_t zbytes = off - zoff;
    int* ci    = (int*)alloc((size_t)e * 4);
    int* bsum  = (int*)alloc(512);
    _Float16* wh = (_Float16*)alloc((size_t)L * 2 * 16384 * 2);
    _Float16* wl = (_Float16*)alloc((size_t)L * 2 * 16384 * 2);

    hipMemsetAsync(deg, 0, zbytes, stream);

    // fused preamble: wsplit | emb->fp16 | degree
    int wtot = L * 2 * 16384;
    int ctot = vocab * HD / 8;
    int nbW = (wtot + 255) / 256;
    int nbC = (ctot + 255) / 256;
    int nbD = (e + 255) / 256;
    k_pre<<<nbW + nbC + nbD, 256, 0, stream>>>(emb, emb16, ctot,
                                               W1, W2, wh, wl, wtot,
                                               dst, deg, e, nbW, nbC);

    int nb = (n + 1023) / 1024;
    k_scan1<<<nb, 1024, 0, stream>>>(deg, rp, bsum, n);
    k_scan2<<<1, 128, 0, stream>>>(bsum, nb);
    k_scan3<<<nb, 1024, 0, stream>>>(rp, bsum, n, e);
    k_fill<<<(e + 255) / 256, 256, 0, stream>>>(src, dst, rp, fillc, ci, e);

    // layer 0: fused embed+GIN via fp16 emb table (TM0=32 blocks)
    k_gin0<<<(n + TM0 - 1) / TM0, 256, 0, stream>>>(
        tok, emb16, xa, rp, ci,
        wh, wl, wh + 16384, wl + 16384,
        b1, b2, n);

    // layers 1..L-1: TM=64 blocks, 512 threads
    const int ngrid = (n + TM - 1) / TM;
    _Float16* xin = xa;
    _Float16* xo  = xb;
    for (int l = 1; l < L; ++l) {
        const _Float16* lw = wh + (size_t)l * 2 * 16384;
        const _Float16* ll = wl + (size_t)l * 2 * 16384;
        k_gin<<<ngrid, 512, 0, stream>>>(
            xin, xo, rp, ci,
            lw, ll, lw + 16384, ll + 16384,
            b1 + (size_t)l * HD, b2 + (size_t)l * HD, n);
        _Float16* t = xin; xin = xo; xo = t;
    }

    k_pool<<<ngraph, 256, 0, stream>>>(xin, batch, out, n);
}

// Round 11
// 397.608 us; speedup vs baseline: 1.0641x; 1.0641x over previous
//
#include <hip/hip_runtime.h>

#define HD   128   // hidden dim
#define TM   32    // node rows per block in the GIN layer kernel
#define SYB  136   // fp16 LDS stride
#define ECAP 512   // staged edges per tile (block avg ~192)

typedef __attribute__((ext_vector_type(8))) short    short8;
typedef __attribute__((ext_vector_type(8))) _Float16 half8;
typedef __attribute__((ext_vector_type(4))) float    float4v;

// split fp32 -> fp16 hi + fp16 lo; v == hi + lo to ~2^-22 rel (lo may be denormal)
__device__ __forceinline__ void split_h16(float v, _Float16& hi, _Float16& lo) {
    hi = (_Float16)v;
    lo = (_Float16)(v - (float)hi);
}

// ------------------------------------------------ fused preamble ----
// weight-split | emb->fp16 table | degree in one launch (independent work)
__global__ void k_pre(const float* __restrict__ emb, _Float16* __restrict__ emb16,
                      int ctot,
                      const float* __restrict__ W1, const float* __restrict__ W2,
                      _Float16* __restrict__ wh, _Float16* __restrict__ wl, int wtot,
                      const int* __restrict__ dst, int* __restrict__ deg, int e,
                      int nbW, int nbC)
{
    int b = blockIdx.x, tx = threadIdx.x;
    if (b < nbW) {
        // ---- weight split into B-frags (fp16 hi/lo)
        // frag idx f = ((ct*4 + kb)*64 + lane)*8 + j holds
        // W[kb*32 + (lane>>4)*8 + j][ct*16 + (lane&15)]  (B-operand of 16x16x32)
        int g = b * 256 + tx;
        if (g < wtot) {
            int f  = g & 16383;
            int m  = (g >> 14) & 1;
            int l  = g >> 15;
            int j    = f & 7;
            int lane = (f >> 3) & 63;
            int kb   = (f >> 9) & 3;
            int ct   = f >> 11;
            int k  = kb * 32 + (lane >> 4) * 8 + j;
            int nn = ct * 16 + (lane & 15);
            const float* W = m ? W2 : W1;
            float v = W[(size_t)l * 16384 + k * 128 + nn];
            _Float16 h, lo; split_h16(v, h, lo);
            wh[g] = h; wl[g] = lo;
        }
    } else if (b < nbW + nbC) {
        // ---- emb fp32 -> fp16 table (VOCAB x HD, 8 elems/thread)
        int g = (b - nbW) * 256 + tx;
        if (g < ctot) {
            const float4* e4 = (const float4*)emb + (size_t)g * 2;
            float4 a = e4[0], c = e4[1];
            half8 h;
            h[0] = (_Float16)a.x; h[1] = (_Float16)a.y; h[2] = (_Float16)a.z; h[3] = (_Float16)a.w;
            h[4] = (_Float16)c.x; h[5] = (_Float16)c.y; h[6] = (_Float16)c.z; h[7] = (_Float16)c.w;
            ((half8*)emb16)[g] = h;
        }
    } else {
        // ---- degree
        int i = (b - nbW - nbC) * 256 + tx;
        if (i < e) atomicAdd(&deg[dst[i]], 1);
    }
}

// ------------------------------------------------------------- CSR build ----
__global__ void k_scan1(const int* __restrict__ deg, int* __restrict__ rp,
                        int* __restrict__ bsum, int n)
{
    __shared__ int s[1024];
    int t = threadIdx.x;
    int i = blockIdx.x * 1024 + t;
    int v = (i < n) ? deg[i] : 0;
    s[t] = v; __syncthreads();
    for (int off = 1; off < 1024; off <<= 1) {
        int tmp = (t >= off) ? s[t - off] : 0;
        __syncthreads();
        s[t] += tmp;
        __syncthreads();
    }
    if (i < n) rp[i] = s[t] - v;
    if (t == 1023) bsum[blockIdx.x] = s[1023];
}

__global__ void k_scan2(int* __restrict__ bsum, int nb)
{
    __shared__ int s[128];
    int t = threadIdx.x;
    int v = (t < nb) ? bsum[t] : 0;
    s[t] = v; __syncthreads();
    for (int off = 1; off < 128; off <<= 1) {
        int tmp = (t >= off) ? s[t - off] : 0;
        __syncthreads();
        s[t] += tmp;
        __syncthreads();
    }
    if (t < nb) bsum[t] = s[t] - v;
}

__global__ void k_scan3(int* __restrict__ rp, const int* __restrict__ bsum, int n, int e)
{
    int i = blockIdx.x * 1024 + threadIdx.x;
    if (i < n) rp[i] += bsum[blockIdx.x];
    if (i == 0) rp[n] = e;
}

__global__ void k_fill(const int* __restrict__ src, const int* __restrict__ dst,
                       const int* __restrict__ rp, int* __restrict__ fill,
                       int* __restrict__ ci, int e)
{
    int i = blockIdx.x * 256 + threadIdx.x;
    if (i < e) {
        int d = dst[i];
        int p = atomicAdd(&fill[d], 1);
        ci[rp[d] + p] = src[i];
    }
}

// ------------------------------------------------------- fused GIN layer ----
// GEMM scheme: A (Y,H) single fp16; W fp16 hi+lo -> 2 MFMA per logical MFMA.
// One fp16 A-tile in LDS: half the ds_reads, ~11 KB LDS.
__global__ __launch_bounds__(256, 4)
void k_gin(const _Float16* __restrict__ xin, _Float16* __restrict__ xout,
           const int* __restrict__ rp, const int* __restrict__ ci,
           const _Float16* __restrict__ w1h, const _Float16* __restrict__ w1l,
           const _Float16* __restrict__ w2h, const _Float16* __restrict__ w2l,
           const float* __restrict__ b1, const float* __restrict__ b2,
           int n)
{
    __shared__ _Float16 sA[TM * SYB];   // Y tile, then H tile (fp16)
    __shared__ int      sCI[ECAP];      // staged neighbor indices for the block

    const int tx   = threadIdx.x;
    const int row0 = blockIdx.x * TM;
    const int wv   = tx >> 6, lane = tx & 63;
    const int quad = lane >> 4, lrow = lane & 15;

    // ---- aggregation: Y[row] = x[row] + sum_{j} x[j]
    {
        const int rl = tx >> 3, part = tx & 7;
        int node = row0 + rl;
        if (node >= n) node = n - 1;             // clamped rows compute garbage, never stored
        const half8* xr = (const half8*)(xin + (size_t)node * HD);
        half8 xs0 = xr[part * 2 + 0];
        half8 xs1 = xr[part * 2 + 1];
        float acc[2][8];
#pragma unroll
        for (int k = 0; k < 8; ++k) { acc[0][k] = (float)xs0[k]; acc[1][k] = (float)xs1[k]; }

        const int e0 = rp[node], e1 = rp[node + 1];
        const int eb0 = rp[row0];
        const int ebN = rp[(row0 + TM < n) ? (row0 + TM) : n];

        for (int t0 = eb0; t0 < ebN; t0 += ECAP) {
            const int t1 = (t0 + ECAP < ebN) ? (t0 + ECAP) : ebN;
            for (int i = tx; i < t1 - t0; i += 256) sCI[i] = ci[t0 + i];
            __syncthreads();

            int a = (e0 > t0) ? e0 : t0;
            int b = (e1 < t1) ? e1 : t1;
            for (int base = a; base < b; base += 8) {
                half8 u[8][2];
#pragma unroll
                for (int q = 0; q < 8; ++q) {    // predicated: masked groups issue no traffic
                    if (base + q < b) {
                        int c = sCI[base + q - t0];
                        const half8* xc = (const half8*)(xin + (size_t)c * HD);
                        u[q][0] = xc[part * 2 + 0];
                        u[q][1] = xc[part * 2 + 1];
                    }
                }
#pragma unroll
                for (int q = 0; q < 8; ++q) {
                    if (base + q < b) {
#pragma unroll
                        for (int k = 0; k < 8; ++k) {
                            acc[0][k] += (float)u[q][0][k];
                            acc[1][k] += (float)u[q][1][k];
                        }
                    }
                }
            }
            __syncthreads();   // all groups done with this sCI tile
        }

        // fp32 -> fp16 into LDS (elems part*16 + q*8 + j)
#pragma unroll
        for (int q = 0; q < 2; ++q) {
            half8 h8;
#pragma unroll
            for (int k = 0; k < 8; ++k) h8[k] = (_Float16)acc[q][k];
            *(half8*)&sA[rl * SYB + part * 16 + q * 8] = h8;
        }
    }

    // B1 hi frags + bias
    half8 Bh[2][4];
    {
        const half8* h8 = (const half8*)w1h;
#pragma unroll
        for (int c = 0; c < 2; ++c)
#pragma unroll
            for (int kb = 0; kb < 4; ++kb)
                Bh[c][kb] = h8[((2 * wv + c) * 4 + kb) * 64 + lane];
    }
    float bb0 = b1[(2 * wv + 0) * 16 + lrow];
    float bb1 = b1[(2 * wv + 1) * 16 + lrow];
    __syncthreads();

    // ---- GEMM1: H = relu(Y @ W1 + b1); rows 0..31, wave cols [32wv, 32wv+32)
    float4v acc1[2][2];
#pragma unroll
    for (int rt = 0; rt < 2; ++rt) {
        acc1[rt][0] = (float4v){bb0, bb0, bb0, bb0};
        acc1[rt][1] = (float4v){bb1, bb1, bb1, bb1};
    }
    {
        const half8* l8 = (const half8*)w1l;
#pragma unroll
        for (int kb = 0; kb < 4; ++kb) {
            half8 Ah[2];
#pragma unroll
            for (int rt = 0; rt < 2; ++rt)
                Ah[rt] = *(const half8*)&sA[(rt * 16 + lrow) * SYB + kb * 32 + quad * 8];
            half8 Bl0 = l8[((2 * wv + 0) * 4 + kb) * 64 + lane];
            half8 Bl1 = l8[((2 * wv + 1) * 4 + kb) * 64 + lane];
#pragma unroll
            for (int rt = 0; rt < 2; ++rt) {
                acc1[rt][0] = __builtin_amdgcn_mfma_f32_16x16x32_f16(Ah[rt], Bh[0][kb], acc1[rt][0], 0, 0, 0);
                acc1[rt][0] = __builtin_amdgcn_mfma_f32_16x16x32_f16(Ah[rt], Bl0,       acc1[rt][0], 0, 0, 0);
                acc1[rt][1] = __builtin_amdgcn_mfma_f32_16x16x32_f16(Ah[rt], Bh[1][kb], acc1[rt][1], 0, 0, 0);
                acc1[rt][1] = __builtin_amdgcn_mfma_f32_16x16x32_f16(Ah[rt], Bl1,       acc1[rt][1], 0, 0, 0);
            }
        }
    }

    // B2 hi frags + bias
    half8 Bh2[2][4];
    {
        const half8* h8 = (const half8*)w2h;
#pragma unroll
        for (int c = 0; c < 2; ++c)
#pragma unroll
            for (int kb = 0; kb < 4; ++kb)
                Bh2[c][kb] = h8[((2 * wv + c) * 4 + kb) * 64 + lane];
    }
    float cb0 = b2[(2 * wv + 0) * 16 + lrow];
    float cb1 = b2[(2 * wv + 1) * 16 + lrow];

    __syncthreads();   // all waves done reading Y from LDS

    // H (relu) -> fp16 into sA (overwrite Y)
#pragma unroll
    for (int rt = 0; rt < 2; ++rt)
#pragma unroll
        for (int c = 0; c < 2; ++c) {
            int col = (2 * wv + c) * 16 + lrow;
#pragma unroll
            for (int r = 0; r < 4; ++r) {
                int row = rt * 16 + quad * 4 + r;
                sA[row * SYB + col] = (_Float16)fmaxf(acc1[rt][c][r], 0.f);
            }
        }
    __syncthreads();

    // ---- GEMM2: X' = relu(H @ W2 + b2)
    float4v acc2[2][2];
#pragma unroll
    for (int rt = 0; rt < 2; ++rt) {
        acc2[rt][0] = (float4v){cb0, cb0, cb0, cb0};
        acc2[rt][1] = (float4v){cb1, cb1, cb1, cb1};
    }
    {
        const half8* l8 = (const half8*)w2l;
#pragma unroll
        for (int kb = 0; kb < 4; ++kb) {
            half8 Ah[2];
#pragma unroll
            for (int rt = 0; rt < 2; ++rt)
                Ah[rt] = *(const half8*)&sA[(rt * 16 + lrow) * SYB + kb * 32 + quad * 8];
            half8 Bl0 = l8[((2 * wv + 0) * 4 + kb) * 64 + lane];
            half8 Bl1 = l8[((2 * wv + 1) * 4 + kb) * 64 + lane];
#pragma unroll
            for (int rt = 0; rt < 2; ++rt) {
                acc2[rt][0] = __builtin_amdgcn_mfma_f32_16x16x32_f16(Ah[rt], Bh2[0][kb], acc2[rt][0], 0, 0, 0);
                acc2[rt][0] = __builtin_amdgcn_mfma_f32_16x16x32_f16(Ah[rt], Bl0,        acc2[rt][0], 0, 0, 0);
                acc2[rt][1] = __builtin_amdgcn_mfma_f32_16x16x32_f16(Ah[rt], Bh2[1][kb], acc2[rt][1], 0, 0, 0);
                acc2[rt][1] = __builtin_amdgcn_mfma_f32_16x16x32_f16(Ah[rt], Bl1,        acc2[rt][1], 0, 0, 0);
            }
        }
    }

    // epilogue: relu + store fp16
#pragma unroll
    for (int rt = 0; rt < 2; ++rt)
#pragma unroll
        for (int c = 0; c < 2; ++c) {
            int col = (2 * wv + c) * 16 + lrow;
#pragma unroll
            for (int r = 0; r < 4; ++r) {
                int node = row0 + rt * 16 + quad * 4 + r;
                if (node < n)
                    xout[(size_t)node * HD + col] = (_Float16)fmaxf(acc2[rt][c][r], 0.f);
            }
        }
}

// ---------------------------------------------- layer-0 fused GIN layer ----
// x0 = emb[tok]: gather tok[src] (4 B, L2-resident) + 32 KB fp16 table (L1).
__global__ __launch_bounds__(256, 4)
void k_gin0(const int* __restrict__ tok, const _Float16* __restrict__ emb16,
            _Float16* __restrict__ xout,
            const int* __restrict__ rp, const int* __restrict__ ci,
            const _Float16* __restrict__ w1h, const _Float16* __restrict__ w1l,
            const _Float16* __restrict__ w2h, const _Float16* __restrict__ w2l,
            const float* __restrict__ b1, const float* __restrict__ b2,
            int n)
{
    __shared__ _Float16 sA[TM * SYB];
    __shared__ int      sCI[ECAP];

    const int tx   = threadIdx.x;
    const int row0 = blockIdx.x * TM;
    const int wv   = tx >> 6, lane = tx & 63;
    const int quad = lane >> 4, lrow = lane & 15;

    // ---- aggregation via fp16 emb-table lookup
    {
        const int rl = tx >> 3, part = tx & 7;
        int node = row0 + rl;
        if (node >= n) node = n - 1;
        int tself = tok[node];
        const half8* er = (const half8*)(emb16 + (size_t)tself * HD);
        half8 xs0 = er[part * 2 + 0];
        half8 xs1 = er[part * 2 + 1];
        float acc[2][8];
#pragma unroll
        for (int k = 0; k < 8; ++k) { acc[0][k] = (float)xs0[k]; acc[1][k] = (float)xs1[k]; }

        const int e0 = rp[node], e1 = rp[node + 1];
        const int eb0 = rp[row0];
        const int ebN = rp[(row0 + TM < n) ? (row0 + TM) : n];

        for (int t0 = eb0; t0 < ebN; t0 += ECAP) {
            const int t1 = (t0 + ECAP < ebN) ? (t0 + ECAP) : ebN;
            for (int i = tx; i < t1 - t0; i += 256) sCI[i] = ci[t0 + i];
            __syncthreads();

            int a = (e0 > t0) ? e0 : t0;
            int b = (e1 < t1) ? e1 : t1;
            for (int base = a; base < b; base += 8) {
                int tq[8];
#pragma unroll
                for (int q = 0; q < 8; ++q) {
                    if (base + q < b) tq[q] = tok[sCI[base + q - t0]];
                }
                half8 u[8][2];
#pragma unroll
                for (int q = 0; q < 8; ++q) {
                    if (base + q < b) {
                        const half8* xc = (const half8*)(emb16 + (size_t)tq[q] * HD);
                        u[q][0] = xc[part * 2 + 0];
                        u[q][1] = xc[part * 2 + 1];
                    }
                }
#pragma unroll
                for (int q = 0; q < 8; ++q) {
                    if (base + q < b) {
#pragma unroll
                        for (int k = 0; k < 8; ++k) {
                            acc[0][k] += (float)u[q][0][k];
                            acc[1][k] += (float)u[q][1][k];
                        }
                    }
                }
            }
            __syncthreads();
        }

#pragma unroll
        for (int q = 0; q < 2; ++q) {
            half8 h8;
#pragma unroll
            for (int k = 0; k < 8; ++k) h8[k] = (_Float16)acc[q][k];
            *(half8*)&sA[rl * SYB + part * 16 + q * 8] = h8;
        }
    }

    // B1 hi frags + bias
    half8 Bh[2][4];
    {
        const half8* h8 = (const half8*)w1h;
#pragma unroll
        for (int c = 0; c < 2; ++c)
#pragma unroll
            for (int kb = 0; kb < 4; ++kb)
                Bh[c][kb] = h8[((2 * wv + c) * 4 + kb) * 64 + lane];
    }
    float bb0 = b1[(2 * wv + 0) * 16 + lrow];
    float bb1 = b1[(2 * wv + 1) * 16 + lrow];
    __syncthreads();

    float4v acc1[2][2];
#pragma unroll
    for (int rt = 0; rt < 2; ++rt) {
        acc1[rt][0] = (float4v){bb0, bb0, bb0, bb0};
        acc1[rt][1] = (float4v){bb1, bb1, bb1, bb1};
    }
    {
        const half8* l8 = (const half8*)w1l;
#pragma unroll
        for (int kb = 0; kb < 4; ++kb) {
            half8 Ah[2];
#pragma unroll
            for (int rt = 0; rt < 2; ++rt)
                Ah[rt] = *(const half8*)&sA[(rt * 16 + lrow) * SYB + kb * 32 + quad * 8];
            half8 Bl0 = l8[((2 * wv + 0) * 4 + kb) * 64 + lane];
            half8 Bl1 = l8[((2 * wv + 1) * 4 + kb) * 64 + lane];
#pragma unroll
            for (int rt = 0; rt < 2; ++rt) {
                acc1[rt][0] = __builtin_amdgcn_mfma_f32_16x16x32_f16(Ah[rt], Bh[0][kb], acc1[rt][0], 0, 0, 0);
                acc1[rt][0] = __builtin_amdgcn_mfma_f32_16x16x32_f16(Ah[rt], Bl0,       acc1[rt][0], 0, 0, 0);
                acc1[rt][1] = __builtin_amdgcn_mfma_f32_16x16x32_f16(Ah[rt], Bh[1][kb], acc1[rt][1], 0, 0, 0);
                acc1[rt][1] = __builtin_amdgcn_mfma_f32_16x16x32_f16(Ah[rt], Bl1,       acc1[rt][1], 0, 0, 0);
            }
        }
    }

    half8 Bh2[2][4];
    {
        const half8* h8 = (const half8*)w2h;
#pragma unroll
        for (int c = 0; c < 2; ++c)
#pragma unroll
            for (int kb = 0; kb < 4; ++kb)
                Bh2[c][kb] = h8[((2 * wv + c) * 4 + kb) * 64 + lane];
    }
    float cb0 = b2[(2 * wv + 0) * 16 + lrow];
    float cb1 = b2[(2 * wv + 1) * 16 + lrow];

    __syncthreads();

#pragma unroll
    for (int rt = 0; rt < 2; ++rt)
#pragma unroll
        for (int c = 0; c < 2; ++c) {
            int col = (2 * wv + c) * 16 + lrow;
#pragma unroll
            for (int r = 0; r < 4; ++r) {
                int row = rt * 16 + quad * 4 + r;
                sA[row * SYB + col] = (_Float16)fmaxf(acc1[rt][c][r], 0.f);
            }
        }
    __syncthreads();

    float4v acc2[2][2];
#pragma unroll
    for (int rt = 0; rt < 2; ++rt) {
        acc2[rt][0] = (float4v){cb0, cb0, cb0, cb0};
        acc2[rt][1] = (float4v){cb1, cb1, cb1, cb1};
    }
    {
        const half8* l8 = (const half8*)w2l;
#pragma unroll
        for (int kb = 0; kb < 4; ++kb) {
            half8 Ah[2];
#pragma unroll
            for (int rt = 0; rt < 2; ++rt)
                Ah[rt] = *(const half8*)&sA[(rt * 16 + lrow) * SYB + kb * 32 + quad * 8];
            half8 Bl0 = l8[((2 * wv + 0) * 4 + kb) * 64 + lane];
            half8 Bl1 = l8[((2 * wv + 1) * 4 + kb) * 64 + lane];
#pragma unroll
            for (int rt = 0; rt < 2; ++rt) {
                acc2[rt][0] = __builtin_amdgcn_mfma_f32_16x16x32_f16(Ah[rt], Bh2[0][kb], acc2[rt][0], 0, 0, 0);
                acc2[rt][0] = __builtin_amdgcn_mfma_f32_16x16x32_f16(Ah[rt], Bl0,        acc2[rt][0], 0, 0, 0);
                acc2[rt][1] = __builtin_amdgcn_mfma_f32_16x16x32_f16(Ah[rt], Bh2[1][kb], acc2[rt][1], 0, 0, 0);
                acc2[rt][1] = __builtin_amdgcn_mfma_f32_16x16x32_f16(Ah[rt], Bl1,        acc2[rt][1], 0, 0, 0);
            }
        }
    }

#pragma unroll
    for (int rt = 0; rt < 2; ++rt)
#pragma unroll
        for (int c = 0; c < 2; ++c) {
            int col = (2 * wv + c) * 16 + lrow;
#pragma unroll
            for (int r = 0; r < 4; ++r) {
                int node = row0 + rt * 16 + quad * 4 + r;
                if (node < n)
                    xout[(size_t)node * HD + col] = (_Float16)fmaxf(acc2[rt][c][r], 0.f);
            }
        }
}

// ------------------------------------------------------------------ pool ----
__global__ void k_pool(const _Float16* __restrict__ x, const int* __restrict__ batch,
                       float* __restrict__ out, int n)
{
    __shared__ float sp[HD];
    int g = blockIdx.x;
    int t = threadIdx.x & (HD - 1);
    int h = threadIdx.x >> 7;          // strand 0/1
    int lo = 0, hi = n;
    while (lo < hi) { int m = (lo + hi) >> 1; if (batch[m] < g) lo = m + 1; else hi = m; }
    int s = lo;
    hi = n;
    while (lo < hi) { int m = (lo + hi) >> 1; if (batch[m] < g + 1) lo = m + 1; else hi = m; }
    int e = lo;
    float sum = 0.f;
    int i = s + h;
    for (; i + 2 < e; i += 4) {
        float v0 = (float)x[(size_t)i * HD + t];
        float v1 = (float)x[(size_t)(i + 2) * HD + t];
        sum += v0 + v1;
    }
    if (i < e) sum += (float)x[(size_t)i * HD + t];
    if (h == 1) sp[t] = sum;
    __syncthreads();
    if (h == 0) {
        int cnt = e - s;
        float tot = sum + sp[t];
        out[(size_t)g * HD + t] = (cnt > 0) ? tot / (float)cnt : 0.f;
    }
}

// ---------------------------------------------------------------- launch ----
extern "C" void kernel_launch(void* const* d_in, const int* in_sizes, int n_in,
                              void* d_out, int out_size, void* d_ws, size_t ws_size,
                              hipStream_t stream)
{
    const int*   tok   = (const int*)d_in[0];
    const int*   eidx  = (const int*)d_in[1];
    const int*   batch = (const int*)d_in[2];
    const float* emb   = (const float*)d_in[3];
    const float* W1    = (const float*)d_in[4];
    const float* b1    = (const float*)d_in[5];
    const float* W2    = (const float*)d_in[6];
    const float* b2    = (const float*)d_in[7];
    float* out = (float*)d_out;

    const int n      = in_sizes[0];
    const int e      = in_sizes[1] / 2;
    const int ngraph = out_size / HD;
    const int L      = in_sizes[4] / (HD * HD);
    const int vocab  = in_sizes[3] / HD;     // in_sizes are ELEMENT counts (fp32)
    const int* src = eidx;
    const int* dst = eidx + e;

    char* w = (char*)d_ws;
    size_t off = 0;
    auto alloc = [&](size_t bytes) -> void* {
        void* p = w + off;
        off = (off + bytes + 255) & ~(size_t)255;
        return p;
    };
    _Float16* xa = (_Float16*)alloc((size_t)(n + TM) * HD * 2);
    _Float16* xb = (_Float16*)alloc((size_t)(n + TM) * HD * 2);
    _Float16* emb16 = (_Float16*)alloc((size_t)vocab * HD * 2);
    int* rp    = (int*)alloc((size_t)(n + 1) * 4);
    // zero-init group: deg, fillc contiguous -> ONE memset
    size_t zoff = off;
    int* deg   = (int*)alloc((size_t)n * 4);
    int* fillc = (int*)alloc((size_t)n * 4);
    size_t zbytes = off - zoff;
    int* ci    = (int*)alloc((size_t)e * 4);
    int* bsum  = (int*)alloc(512);
    _Float16* wh = (_Float16*)alloc((size_t)L * 2 * 16384 * 2);
    _Float16* wl = (_Float16*)alloc((size_t)L * 2 * 16384 * 2);

    hipMemsetAsync(deg, 0, zbytes, stream);

    // fused preamble: wsplit | emb->fp16 | degree
    int wtot = L * 2 * 16384;
    int ctot = vocab * HD / 8;
    int nbW = (wtot + 255) / 256;
    int nbC = (ctot + 255) / 256;
    int nbD = (e + 255) / 256;
    k_pre<<<nbW + nbC + nbD, 256, 0, stream>>>(emb, emb16, ctot,
                                               W1, W2, wh, wl, wtot,
                                               dst, deg, e, nbW, nbC);

    int nb = (n + 1023) / 1024;
    k_scan1<<<nb, 1024, 0, stream>>>(deg, rp, bsum, n);
    k_scan2<<<1, 128, 0, stream>>>(bsum, nb);
    k_scan3<<<nb, 1024, 0, stream>>>(rp, bsum, n, e);
    k_fill<<<(e + 255) / 256, 256, 0, stream>>>(src, dst, rp, fillc, ci, e);

    const int ngrid = (n + TM - 1) / TM;

    // layer 0: fused embed+GIN via fp16 emb table
    k_gin0<<<ngrid, 256, 0, stream>>>(
        tok, emb16, xa, rp, ci,
        wh, wl, wh + 16384, wl + 16384,
        b1, b2, n);

    _Float16* xin = xa;
    _Float16* xo  = xb;
    for (int l = 1; l < L; ++l) {
        const _Float16* lw = wh + (size_t)l * 2 * 16384;
        const _Float16* ll = wl + (size_t)l * 2 * 16384;
        k_gin<<<ngrid, 256, 0, stream>>>(
            xin, xo, rp, ci,
            lw, ll, lw + 16384, ll + 16384,
            b1 + (size_t)l * HD, b2 + (size_t)l * HD, n);
        _Float16* t = xin; xin = xo; xo = t;
    }

    k_pool<<<ngraph, 256, 0, stream>>>(xin, batch, out, n);
}